// Round 6
// baseline (4960.070 us; speedup 1.0000x reference)
//
#include <hip/hip_runtime.h>

#define NLAYER 6
#define NB     128     // batch
#define NT     512     // seq len
#define DIN    128     // layer-0 input size
#define NH     256     // hidden
#define NBLK   192     // 6 layers x 8 batch-groups x 4 col-quarter blocks
// Tagged h-ring: each value is one 4B word = (bf16<<16)|step_tag.
// Slot = [128 batch rows][256 words] = [128][128 u64].
#define TSLOT_U64 (NB*NH/2)
#define PITCH  520     // LDS B-plane row pitch in bf16 (1040B; 16B-aligned rows)

typedef __attribute__((ext_vector_type(8))) short short8;
typedef __attribute__((ext_vector_type(4))) float f32x4;
typedef __attribute__((ext_vector_type(2))) float f32x2;
typedef __attribute__((ext_vector_type(4))) unsigned uint4v;
typedef unsigned long long u64;

__device__ __forceinline__ unsigned f2bf2(float lo, float hi){
  unsigned a = __float_as_uint(lo), b = __float_as_uint(hi);
  a = (a + 0x7fffu + ((a>>16)&1u)) >> 16;   // RNE bf16
  b = (b + 0x7fffu + ((b>>16)&1u)) >> 16;
  return a | (b<<16);
}
__device__ __forceinline__ u64 f2bf4(float a, float b, float c, float d){
  return (u64)f2bf2(a,b) | ((u64)f2bf2(c,d) << 32);
}
__device__ __forceinline__ short8 pack16(u64 lo, u64 hi){
  union { u64 u[2]; short8 v; } w; w.u[0]=lo; w.u[1]=hi; return w.v;
}
// 8 consecutive fp32 -> one MFMA bf16 fragment (4 VGPRs)
__device__ __forceinline__ short8 ld8f_frag(const float* p){
  f32x4 a = *(const f32x4*)p;
  f32x4 b = *(const f32x4*)(p+4);
  return pack16(f2bf4(a[0],a[1],a[2],a[3]), f2bf4(b[0],b[1],b[2],b[3]));
}
__device__ __forceinline__ float sigmf(float v){ return 1.0f/(1.0f + __expf(-v)); }
__device__ __forceinline__ float tanhfast(float v){
  v = fminf(fmaxf(v, -15.0f), 15.0f);
  float e = __expf(2.0f*v);
  return (e - 1.0f)/(e + 1.0f);
}
// agent-scope flags (rare paths: WAR acks only)
__device__ __forceinline__ int ld_flag(const int* p){
  return __hip_atomic_load(p, __ATOMIC_RELAXED, __HIP_MEMORY_SCOPE_AGENT);
}
__device__ __forceinline__ void st_flag(int* p, int v){
  __hip_atomic_store(p, v, __ATOMIC_RELAXED, __HIP_MEMORY_SCOPE_AGENT);
}
__device__ __forceinline__ unsigned tagw(float f, unsigned tag){
  unsigned a = __float_as_uint(f);
  return ((a + 0x7fffu + ((a>>16)&1u)) & 0xffff0000u) | tag;   // RNE bf16 hi16
}
__device__ __forceinline__ unsigned strip2(u64 q_){
  return __builtin_amdgcn_perm((unsigned)(q_>>32), (unsigned)q_, 0x07060302u);
}

// Publish: L2 leg FIRST (fast same-XCD detect), THEN fabric write-through
// (authoritative copy for cross-XCD progress). Same value both legs, so
// store-store order only affects visibility timing, never the value.
__device__ __forceinline__ void st8_pub(u64* p, u64 v){
  asm volatile(
    "global_store_dwordx2 %0, %1, off sc0\n\t"
    "global_store_dwordx2 %0, %1, off sc0 sc1"
    :: "v"(p), "v"(v) : "memory");
}
// 32B tagged sample, fast: caller just ran buffer_inv sc0 (L1 invalidate),
// so plain loads are served L2-fresh.
__device__ __forceinline__ void ld32_fast(const u64* base, uint4v& a, uint4v& b){
  asm volatile(
    "global_load_dwordx4 %0, %2, off\n\t"
    "global_load_dwordx4 %1, %2, off offset:16\n\t"
    "s_waitcnt vmcnt(0)"
    : "=&v"(a), "=&v"(b) : "v"(base) : "memory");
}
// authoritative: bypass L1+L2, read the MALL/fabric copy
__device__ __forceinline__ void ld32_auth(const u64* base, uint4v& a, uint4v& b){
  asm volatile(
    "global_load_dwordx4 %0, %2, off sc0 sc1\n\t"
    "global_load_dwordx4 %1, %2, off offset:16 sc0 sc1\n\t"
    "s_waitcnt vmcnt(0)"
    : "=&v"(a), "=&v"(b) : "v"(base) : "memory");
}
__device__ __forceinline__ unsigned chk(uint4v a, uint4v b, unsigned tag){
  uint4v xa = a ^ tag, xb = b ^ tag;
  return (xa[0]|xa[1]|xa[2]|xa[3]|xb[0]|xb[1]|xb[2]|xb[3]) & 0xffffu;
}
__device__ __forceinline__ short8 strip8(uint4v a, uint4v b){
  union { uint4v v; u64 u[2]; } ua, ub; ua.v = a; ub.v = b;
  union { unsigned u[4]; short8 v; } o;
  o.u[0] = strip2(ua.u[0]); o.u[1] = strip2(ua.u[1]);
  o.u[2] = strip2(ub.u[0]); o.u[3] = strip2(ub.u[1]);
  return o.v;
}

// Cohort (l,bg) = 4 blocks x 512 thr; block q owns output cols [64q,64q+64).
// Wave w: ks=w&3 K-slice, cs=w>>2 col-sub for MFMA; after LDS reduction wave w
// owns final cols [64q+8w, +8). Own h-quarter returns via LDS only; the 3
// partner quarters (4KB each) cross CUs via tagged dual-scope stores.
template<int NKX>
__device__ __forceinline__ void lstm_run(
    const float* __restrict__ x,  const float* __restrict__ h0,
    const float* __restrict__ c0, const float* __restrict__ wx,
    const float* __restrict__ wh, const float* __restrict__ bi,
    const float* __restrict__ bh, float* __restrict__ out,
    int* __restrict__ acks, u64* __restrict__ ring,
    short (*plane)[16*PITCH], float* __restrict__ part,
    int Wv, int l, int bg, int q)
{
  constexpr int KX   = NKX*32;        // 128 / 256
  constexpr int KTOT = KX + NH;       // 384 / 512
  constexpr int KS   = KTOT/4;        // per-wave K-slice: 96 / 128
  constexpr int NKT  = KS/32;         // 3 / 4 MFMA k-iters
  const int tid  = threadIdx.x;
  const int lane = tid & 63;
  const int w    = tid >> 6;          // wave 0..7
  const int ks   = w & 3;
  const int cs   = w >> 2;
  const int l15  = lane & 15;
  const int quad = lane >> 4;
  const int bloc = bg*16 + l15;
  const int gcol = q*64 + w*8 + quad*2;   // gate-owner's 2 output cols
  const int Wm   = Wv - 1;

  // ---- A fragments: stationary [gate][tile][kt] over combined [x|h] K ----
  short8 A[4][2][NKT];
  #pragma unroll
  for (int g = 0; g < 4; ++g){
    #pragma unroll
    for (int tc = 0; tc < 2; ++tc){
      const int row = g*NH + q*64 + cs*32 + tc*16 + l15;
      #pragma unroll
      for (int kt = 0; kt < NKT; ++kt){
        const int k0 = ks*KS + kt*32 + quad*8;
        A[g][tc][kt] = (k0 < KX) ? ld8f_frag(wx + (size_t)row*KX + k0)
                                 : ld8f_frag(wh + (size_t)row*NH + (k0 - KX));
      }
    }
  }

  float bs[4][2], cc2[2];
  #pragma unroll
  for (int g = 0; g < 4; ++g){
    f32x2 a = *(const f32x2*)(bi + g*NH + gcol);
    f32x2 b = *(const f32x2*)(bh + g*NH + gcol);
    bs[g][0] = a[0]+b[0]; bs[g][1] = a[1]+b[1];
  }
  { f32x2 cv = *(const f32x2*)(c0 + ((size_t)l*NB + bloc)*NH + gcol);
    cc2[0] = cv[0]; cc2[1] = cv[1]; }

  const u64* ringP = (l > 0) ? ring + (size_t)(l-1)*Wv*TSLOT_U64 : nullptr;
  u64*       ringL = ring + (size_t)l*Wv*TSLOT_U64;
  const int* ackOwn  = acks + (l*8 + bg)*4;
  int*       ackPrev = acks + ((l>0?l-1:0)*8 + bg)*4 + q;
  int ackmin = 0;

  // staging lane geometry
  const int xr  = 2*w + (lane>>5);    // x-plane stager row (l>=1)
  const int xc  = (lane&31)*8;        // x cols [xc, xc+8)
  const int hr0 = tid >> 5;           // t=0 h0 / layer-0 x stager row
  const int hc0 = tid & 31;
  const int qrel = w >> 1, hp = w & 1;          // partner poll (waves 0..5)
  const int qp   = qrel + (qrel >= q ? 1 : 0);  // actual partner quarter
  const int prow = hp*8 + (lane>>3);
  const int pc   = (lane&7)*8;

  for (int t = 0; t < NT; ++t){
    const int slot  = t & Wm;
    const int pslot = (t-1) & Wm;

    // WAR wrap guard: layer l+1's 4 blocks must have consumed slot t-Wv.
    if (l < NLAYER-1 && t >= Wv){
      const int need = t - Wv + 1;
      if (ackmin < need){
        int v = 0, guard = 0;
        for (;;){
          v = (lane < 4) ? ld_flag(ackOwn + lane) : 0x7fffffff;
          if (__ballot(v >= need) == ~0ull) break;
          __builtin_amdgcn_s_sleep(1);
          if (++guard > (1<<20)) break;
        }
        int m = v;
        #pragma unroll
        for (int o = 2; o; o >>= 1) m = min(m, __shfl_xor(m, o));
        ackmin = __shfl(m, 0);
      }
    }

    short* pl = plane[t&1];

    // ---- layer 0: x_t from global (plain cached loads), every step ----
    if constexpr (NKX == 4){
      const float* px = x + ((size_t)(bg*16 + hr0)*NT + t)*DIN + hc0*4;
      f32x4 xv = *(const f32x4*)px;
      *(u64*)(pl + hr0*PITCH + hc0*4) = f2bf4(xv[0],xv[1],xv[2],xv[3]);
    }

    if (t == 0){
      // h region from h0 (global)
      const float* ph = h0 + ((size_t)l*NB + bg*16 + hr0)*NH + hc0*8;
      f32x4 a = *(const f32x4*)ph;
      f32x4 b = *(const f32x4*)(ph+4);
      *(short8*)(pl + hr0*PITCH + KX + hc0*8) =
          pack16(f2bf4(a[0],a[1],a[2],a[3]), f2bf4(b[0],b[1],b[2],b[3]));
      if constexpr (NKX == 8){
        const u64* xb = ringP + (size_t)slot*TSLOT_U64 + (size_t)(bg*16 + xr)*128 + (lane&31)*4;
        uint4v qa, qb; int it = 0, guard = 0;
        for (;;){
          ++it;
          const bool auth = (it >= 4) && ((it & 3) == 0);
          if (!auth) asm volatile("buffer_inv sc0" ::: "memory");
          if (auth) ld32_auth(xb, qa, qb); else ld32_fast(xb, qa, qb);
          if (__ballot(chk(qa, qb, 1u) == 0u) == ~0ull) break;
          if ((it & 7) == 7) __builtin_amdgcn_s_sleep(1);
          if (++guard > (1<<20)) break;
        }
        *(short8*)(pl + xr*PITCH + xc) = strip8(qa, qb);
      }
    } else {
      // merged tagged poll: x (l>=1, all waves) + partner quarters (waves 0-5)
      const bool needP = (w < 6);
      uint4v xa, xb2, pa, pb;
      const u64* xbase = nullptr;
      if constexpr (NKX == 8)
        xbase = ringP + (size_t)slot*TSLOT_U64 + (size_t)(bg*16 + xr)*128 + (lane&31)*4;
      const u64* pbase = ringL + (size_t)pslot*TSLOT_U64 + (size_t)(bg*16 + prow)*128 + qp*32 + (lane&7)*4;
      bool okx = (NKX == 4), okp = !needP;
      const unsigned xt = (unsigned)(t+1), ptag = (unsigned)t;
      int it = 0, guard = 0;
      while (!(okx & okp)){
        ++it;
        const bool auth = (it >= 4) && ((it & 3) == 0);
        if (!auth) asm volatile("buffer_inv sc0" ::: "memory");
        if (!okx){ if (auth) ld32_auth(xbase, xa, xb2); else ld32_fast(xbase, xa, xb2); }
        if (!okp){ if (auth) ld32_auth(pbase, pa, pb);  else ld32_fast(pbase, pa, pb); }
        if (!okx) okx = (__ballot(chk(xa, xb2, xt) == 0u) == ~0ull);
        if (!okp) okp = (__ballot(chk(pa, pb, ptag) == 0u) == ~0ull);
        if (okx & okp) break;
        if ((it & 7) == 7) __builtin_amdgcn_s_sleep(1);
        if (++guard > (1<<20)) break;
      }
      if constexpr (NKX == 8)
        *(short8*)(pl + xr*PITCH + xc) = strip8(xa, xb2);
      if (needP)
        *(short8*)(pl + prow*PITCH + KX + qp*64 + pc) = strip8(pa, pb);
    }
    __syncthreads();   // barrier A: B-plane complete; partials consumable

    if constexpr (NKX == 8){
      if (((t & 7) == 7) && tid == 0) st_flag(ackPrev, t+1);   // amortized ack
    }

    // ---- MFMA partials over this wave's K-slice ----
    f32x4 acc[4][2];
    #pragma unroll
    for (int g = 0; g < 4; ++g){ acc[g][0] = (f32x4){0,0,0,0}; acc[g][1] = (f32x4){0,0,0,0}; }
    #pragma unroll
    for (int kt = 0; kt < NKT; ++kt){
      short8 B = *(const short8*)(pl + l15*PITCH + ks*KS + kt*32 + quad*8);
      #pragma unroll
      for (int g = 0; g < 4; ++g){
        acc[g][0] = __builtin_amdgcn_mfma_f32_16x16x32_bf16(A[g][0][kt], B, acc[g][0], 0,0,0);
        acc[g][1] = __builtin_amdgcn_mfma_f32_16x16x32_bf16(A[g][1][kt], B, acc[g][1], 0,0,0);
      }
    }

    // ---- partials -> LDS [j=g*8+tc*4+r][w][lane] (lane-contiguous b32) ----
    #pragma unroll
    for (int g = 0; g < 4; ++g)
      #pragma unroll
      for (int tc = 0; tc < 2; ++tc)
        #pragma unroll
        for (int r = 0; r < 4; ++r)
          part[(g*8 + tc*4 + r)*512 + w*64 + lane] = acc[g][tc][r];
    __syncthreads();   // barrier B: partials complete

    // ---- reduce 4 K-slices + gates (wave w owns cols 64q+8w .. +8) ----
    float hv[2];
    #pragma unroll
    for (int cb = 0; cb < 2; ++cb){
      const int c   = w*8 + quad*2 + cb;     // col within this 64-col quarter
      const int csN = c >> 5, cl = c & 31;
      const int tcN = cl >> 4, qm = (cl >> 2) & 3, r = cl & 3;
      float pre[4];
      #pragma unroll
      for (int g = 0; g < 4; ++g){
        const int base = (g*8 + tcN*4 + r)*512 + (csN*4)*64 + qm*16 + l15;
        float s0 = part[base]       + part[base + 64];
        float s1 = part[base + 128] + part[base + 192];
        pre[g] = s0 + s1 + bs[g][cb];
      }
      float ig = sigmf(pre[0]);
      float fg = sigmf(pre[1]);
      float gv = tanhfast(pre[2]);
      float og = sigmf(pre[3]);
      float cn = fg*cc2[cb] + ig*gv;
      cc2[cb] = cn;
      hv[cb] = og * tanhfast(cn);
    }

    // ---- publish (tagged, dual-scope, fire-and-forget) + own-write via LDS ----
    {
      const unsigned otag = (unsigned)(t+1);
      u64 pw = (u64)tagw(hv[0], otag) | ((u64)tagw(hv[1], otag) << 32);
      st8_pub(ringL + (size_t)slot*TSLOT_U64 + (size_t)bloc*128 + (gcol>>1), pw);
    }
    *(unsigned*)(plane[(t+1)&1] + l15*PITCH + KX + gcol) = f2bf2(hv[0], hv[1]);
    if (t == NT-1){
      f32x2 ov; ov[0] = hv[0]; ov[1] = hv[1];
      *(f32x2*)(out + ((size_t)l*NB + bloc)*NH + gcol) = ov;
    }
  }
}

__global__ __launch_bounds__(512, 2)
void lstm_pipe(const float* __restrict__ x,   const float* __restrict__ h0,
               const float* __restrict__ c0,  const float* __restrict__ wih0,
               const float* __restrict__ wih, const float* __restrict__ whh,
               const float* __restrict__ bih, const float* __restrict__ bhh,
               float* __restrict__ out, int* __restrict__ acks,
               u64* __restrict__ ring, int Wv)
{
  // bid = bg + 8*(l*4 + q): with bid%8 XCD round-robin each bg's entire
  // pipeline (24 blocks) shares one XCD/L2. Speed heuristic only — the
  // authoritative sc0 sc1 samples keep any placement correct.
  __shared__ short plane[2][16*PITCH];   // [dbuf][16 rows x 520 bf16]
  __shared__ float part[32*512];         // K-split partial sums (64KB)
  const int bid = blockIdx.x;
  const int bg  = bid & 7;
  const int jj  = bid >> 3;
  const int l   = jj >> 2;
  const int q   = jj & 3;

  if (l == 0)
    lstm_run<4>(x, h0, c0, wih0, whh, bih, bhh,
                out, acks, ring, plane, part, Wv, 0, bg, q);
  else
    lstm_run<8>(x, h0, c0,
                wih + (size_t)(l-1)*(4*NH*NH),
                whh + (size_t)l*(4*NH*NH),
                bih + (size_t)l*(4*NH),
                bhh + (size_t)l*(4*NH),
                out, acks, ring, plane, part, Wv, l, bg, q);
}

extern "C" void kernel_launch(void* const* d_in, const int* in_sizes, int n_in,
                              void* d_out, int out_size, void* d_ws, size_t ws_size,
                              hipStream_t stream)
{
  (void)in_sizes; (void)n_in; (void)out_size;
  const float* x    = (const float*)d_in[0];
  const float* h0   = (const float*)d_in[1];
  const float* c0   = (const float*)d_in[2];
  const float* wih0 = (const float*)d_in[3];
  const float* wih  = (const float*)d_in[4];
  const float* whh  = (const float*)d_in[5];
  const float* bih  = (const float*)d_in[6];
  const float* bhh  = (const float*)d_in[7];

  // Ring depth 32 (25.2MB tagged). Partner reads are lockstep (skew<=1);
  // the cross-layer consumer is ack-gated (amortized every 8 steps).
  int Wv = 32;
  size_t ringB;
  for (;;){
    ringB = (size_t)NLAYER*Wv*TSLOT_U64*8;
    if (8192 + ringB <= ws_size || Wv <= 8) break;
    Wv >>= 1;
  }

  int* acks = (int*)d_ws;                    // 192 ints, padded to 8KB
  u64* ring = (u64*)((char*)d_ws + 8192);

  // Ring MUST be cleared every launch: a graph replay would otherwise find
  // the previous run's tags and accept stale data. Tag 0 never validates.
  (void)hipMemsetAsync(d_ws, 0, 8192 + ringB, stream);
  hipLaunchKernelGGL(lstm_pipe, dim3(NBLK), dim3(512), 0, stream,
                     x, h0, c0, wih0, wih, whh, bih, bhh,
                     (float*)d_out, acks, ring, Wv);
}

// Round 7
// 3831.023 us; speedup vs baseline: 1.2947x; 1.2947x over previous
//
#include <hip/hip_runtime.h>

#define NLAYER 6
#define NB     128     // batch
#define NT     512     // seq len
#define DIN    128     // layer-0 input size
#define NH     256     // hidden
#define NBLK   192     // 6 layers x 8 batch-groups x 4 blocks
// Tagged ring: each h value is one 4B word = (bf16<<16)|step_tag.
// Slot = [128 batch rows][256 words] = 128KB = 16384 u64. Plane (one bg) =
// 16 rows x 1KB = 2048 u64.
#define TSLOT_U64 (NB*NH/2)

typedef __attribute__((ext_vector_type(8))) short short8;
typedef __attribute__((ext_vector_type(4))) float f32x4;
typedef __attribute__((ext_vector_type(4))) unsigned uint4v;
typedef unsigned long long u64;

__device__ __forceinline__ unsigned f2bf2(float lo, float hi){
  unsigned a = __float_as_uint(lo), b = __float_as_uint(hi);
  a = (a + 0x7fffu + ((a>>16)&1u)) >> 16;   // RNE bf16
  b = (b + 0x7fffu + ((b>>16)&1u)) >> 16;
  return a | (b<<16);
}
__device__ __forceinline__ u64 f2bf4(float a, float b, float c, float d){
  return (u64)f2bf2(a,b) | ((u64)f2bf2(c,d) << 32);
}
__device__ __forceinline__ short8 pack16(u64 lo, u64 hi){
  union { u64 u[2]; short8 v; } w; w.u[0]=lo; w.u[1]=hi; return w.v;
}
// 8 consecutive fp32 -> one MFMA bf16 fragment (4 VGPRs)
__device__ __forceinline__ short8 ld8f_frag(const float* p){
  f32x4 a = *(const f32x4*)p;
  f32x4 b = *(const f32x4*)(p+4);
  return pack16(f2bf4(a[0],a[1],a[2],a[3]), f2bf4(b[0],b[1],b[2],b[3]));
}

__device__ __forceinline__ float sigmf(float v){ return 1.0f/(1.0f + __expf(-v)); }
__device__ __forceinline__ float tanhfast(float v){
  v = fminf(fmaxf(v, -15.0f), 15.0f);
  float e = __expf(2.0f*v);
  return (e - 1.0f)/(e + 1.0f);
}

// agent-scope (fabric-coherent) flag ops — rare paths only (WAR acks)
__device__ __forceinline__ int ld_flag(const int* p){
  return __hip_atomic_load(p, __ATOMIC_RELAXED, __HIP_MEMORY_SCOPE_AGENT);
}
__device__ __forceinline__ void st_flag(int* p, int v){
  __hip_atomic_store(p, v, __ATOMIC_RELAXED, __HIP_MEMORY_SCOPE_AGENT);
}

// one h value + step tag -> self-validating 4B word
__device__ __forceinline__ unsigned tagw(float f, unsigned tag){
  unsigned a = __float_as_uint(f);
  return ((a + 0x7fffu + ((a>>16)&1u)) & 0xffff0000u) | tag;   // RNE bf16 in hi16
}
// strip tags: one tagged u64 (2 words) -> one packed u32 (2 bf16)
__device__ __forceinline__ unsigned strip2(u64 q){
  return __builtin_amdgcn_perm((unsigned)(q>>32), (unsigned)q, 0x07060302u);
}

// ---- cache-policy-controlled plane samples -------------------------------
// FAST sample: caller has just issued buffer_inv sc0 (L1 invalidate), so
// these PLAIN loads are served by the XCD L2 — which the producer's sc0
// store leg (issued FIRST, see st16_pub) dirtied within ~100-200cy.
__device__ __forceinline__ void ld4x16_fast(const u64* base, uint4v q[4]){
  asm volatile(
    "global_load_dwordx4 %0, %4, off\n\t"
    "global_load_dwordx4 %1, %4, off offset:1024\n\t"
    "global_load_dwordx4 %2, %4, off offset:2048\n\t"
    "global_load_dwordx4 %3, %4, off offset:3072\n\t"
    "s_waitcnt vmcnt(0)"
    : "=&v"(q[0]), "=&v"(q[1]), "=&v"(q[2]), "=&v"(q[3])
    : "v"(base) : "memory");
}
// AUTHORITATIVE sample: sc0 sc1 bypasses L1+L2, reads the fabric/MALL copy.
// Guarantees progress even if producer and consumer sit on different XCDs.
__device__ __forceinline__ void ld4x16_auth(const u64* base, uint4v q[4]){
  asm volatile(
    "global_load_dwordx4 %0, %4, off sc0 sc1\n\t"
    "global_load_dwordx4 %1, %4, off offset:1024 sc0 sc1\n\t"
    "global_load_dwordx4 %2, %4, off offset:2048 sc0 sc1\n\t"
    "global_load_dwordx4 %3, %4, off offset:3072 sc0 sc1\n\t"
    "s_waitcnt vmcnt(0)"
    : "=&v"(q[0]), "=&v"(q[1]), "=&v"(q[2]), "=&v"(q[3])
    : "v"(base) : "memory");
}
// Dual publish, L2 LEG FIRST: the sc0 store dirties the shared XCD L2
// immediately (fast same-XCD detect); the sc0 sc1 leg then writes through
// to the fabric (authoritative copy, cross-XCD progress). Same value both
// legs, so ordering only affects visibility timing, never the value.
// (Round-5 bug: legs were swapped — same-address ordering then delayed the
// L2 copy behind the fabric write, so the fast tier never carried fresh data.)
__device__ __forceinline__ void st16_pub(u64* p, uint4v v){
  asm volatile(
    "global_store_dwordx4 %0, %1, off sc0\n\t"
    "global_store_dwordx4 %0, %1, off sc0 sc1"
    :: "v"(p), "v"(v) : "memory");
}

// MFMA B-fragment from a staged LDS plane (row pitch 132 u32 = 528B).
__device__ __forceinline__ short8 lds_frag(const unsigned* __restrict__ buf, int row, int soff){
  return *(const short8*)((const short*)buf + row*264 + soff);
}

// Block = 4 slices x 16 batch rows. Wave wv owns slice s = b*4+wv. h/x are
// staged once per block into LDS via POLLING tagged loads (the stage IS the
// sync); A stationary in regs; publish is fire-and-forget dual-scope stores.
template<int NKX>
__device__ __forceinline__ void lstm_run(
    const float* __restrict__ x,  const float* __restrict__ h0,
    const float* __restrict__ c0, const float* __restrict__ wx,
    const float* __restrict__ wh, const float* __restrict__ bi,
    const float* __restrict__ bh, float* __restrict__ out,
    int* __restrict__ acks, u64* __restrict__ ring, unsigned (*ldsb)[2112],
    int Wv, int l, int bg, int s, int wv, int lane)
{
  constexpr int KIT  = NKX + 8;      // total k-iterations (12 or 16)
  constexpr int KX   = NKX*32;       // input width (128 or 256)
  constexpr bool HASX = (NKX == 8);  // x comes from the prev-layer ring
  const int l15  = lane & 15;
  const int quad = lane >> 4;
  const int bloc = bg*16 + l15;      // this lane's batch row
  const int jcol = s*16 + quad*4;    // this lane's first hidden col
  const int Wm   = Wv - 1;

  // ---- A fragments: stationary (4 gates x KIT kts x 4 VGPR) ----
  short8 A[4][KIT];
  #pragma unroll
  for (int q = 0; q < 4; ++q){
    const float* wrow_x = wx + (size_t)(q*NH + s*16 + l15)*KX;
    const float* wrow_h = wh + (size_t)(q*NH + s*16 + l15)*NH;
    #pragma unroll
    for (int kt = 0; kt < KIT; ++kt){
      int k0 = kt*32 + quad*8;
      A[q][kt] = (k0 < KX) ? ld8f_frag(wrow_x + k0)
                           : ld8f_frag(wrow_h + (k0 - KX));
    }
  }

  f32x4 bsv[4];
  #pragma unroll
  for (int q = 0; q < 4; ++q){
    f32x4 a = *(const f32x4*)(bi + q*NH + jcol);
    f32x4 b = *(const f32x4*)(bh + q*NH + jcol);
    bsv[q] = a + b;
  }
  float cc[4];
  {
    f32x4 cv = *(const f32x4*)(c0 + ((size_t)l*NB + bloc)*NH + jcol);
    cc[0]=cv[0]; cc[1]=cv[1]; cc[2]=cv[2]; cc[3]=cv[3];
  }

  const int* ackOwn = acks + (l*8 + bg)*16;                     // layer l+1 watermarks
  int* ackPrevW = HASX ? acks + ((l-1)*8 + bg)*16 + s : nullptr;
  const u64* ringPrev = HASX ? ring + (size_t)(l-1)*Wv*TSLOT_U64 : nullptr;
  u64*       ringOwn  = ring + (size_t)l*Wv*TSLOT_U64;
  const bool lastL = (l == NLAYER-1);
  const bool wrap  = (Wv < NT);
  int ackmin = 0;

  for (int t = 0; t < NT; ++t){
    const int slot  = t & Wm;
    const int pslot = (t-1) & Wm;

    // WAR guard (wrap only): layer l+1 must have consumed slot t-Wv.
    // Consumers ack every 8 steps; cached watermark -> fabric poll ~1/8 steps.
    if (wrap && !lastL && t >= Wv){
      const int need = t - Wv + 1;
      if (ackmin < need){
        int v = 0, guard = 0;
        for (;;){
          v = (lane < 16) ? ld_flag(ackOwn + lane) : 0x7fffffff;
          if (__ballot(v >= need) == ~0ull) break;
          __builtin_amdgcn_s_sleep(1);
          if (++guard > (1<<22)) break;
        }
        int m = v;
        #pragma unroll
        for (int o = 8; o; o >>= 1) m = min(m, __shfl_xor(m, o));
        ackmin = __shfl(m, 0);
      }
    }

    short8 Bx[NKX];
    if constexpr (!HASX){
      // layer 0: x is a plain cached load (x is read-only, so a reload after
      // any L1 invalidation inside the spin is still correct)
      const float* px = x + ((size_t)bloc*NT + t)*DIN + quad*8;
      #pragma unroll
      for (int k = 0; k < NKX; ++k) Bx[k] = ld8f_frag(px + k*32);
    }

    // ---- polling stage: L1-inv + plain loads (L2-served fast path),
    // sc0 sc1 authoritative sample every 8th iteration ----
    const u64* srcX = HASX ? ringPrev + (size_t)slot*TSLOT_U64 + bg*2048 : nullptr;
    const u64* srcH = (t > 0) ? ringOwn + (size_t)pslot*TSLOT_U64 + bg*2048 : nullptr;
    unsigned* ldsX = ldsb[(t&1)*2 + 0];
    unsigned* ldsH = ldsb[(t&1)*2 + 1];
    const u64* bx = HASX ? srcX + (size_t)wv*512 + (size_t)lane*2 : nullptr;
    const u64* bh = srcH ? srcH + (size_t)wv*512 + (size_t)lane*2 : nullptr;
    uint4v qx[4], qh[4];
    {
      bool okx = !HASX, okh = (srcH == nullptr);
      const unsigned xtag = (unsigned)(t+1), htag = (unsigned)t;
      int it = 0, guard = 0;
      while (!(okx & okh)){
        ++it;
        const bool auth = (it >= 8) && ((it & 7) == 0);
        if (!auth) asm volatile("buffer_inv sc0" ::: "memory");  // L1 inv -> L2-fresh
        if (!okh){ if (auth) ld4x16_auth(bh, qh); else ld4x16_fast(bh, qh); }
        if (!okx){ if (auth) ld4x16_auth(bx, qx); else ld4x16_fast(bx, qx); }
        if (!okh){
          unsigned bad = 0;
          #pragma unroll
          for (int c = 0; c < 4; ++c){
            uint4v xq = qh[c] ^ htag;
            bad |= xq[0] | xq[1] | xq[2] | xq[3];
          }
          okh = (__ballot((bad & 0xffffu) == 0u) == ~0ull);
        }
        if (!okx){
          unsigned bad = 0;
          #pragma unroll
          for (int c = 0; c < 4; ++c){
            uint4v xq = qx[c] ^ xtag;
            bad |= xq[0] | xq[1] | xq[2] | xq[3];
          }
          okx = (__ballot((bad & 0xffffu) == 0u) == ~0ull);
        }
        if (okx & okh) break;
        if ((it & 15) == 15) __builtin_amdgcn_s_sleep(1);
        if (++guard > (1<<22)) break;   // failsafe only
      }
    }
    // strip tags -> packed bf16 planes in LDS (lane-contiguous: conflict-free)
    if constexpr (HASX){
      #pragma unroll
      for (int c = 0; c < 4; ++c){
        union { uint4v v; u64 d[2]; } uq; uq.v = qx[c];
        *(u64*)(ldsX + (wv*4+c)*132 + lane*2) =
            (u64)strip2(uq.d[0]) | ((u64)strip2(uq.d[1]) << 32);
      }
    }
    if (srcH){
      #pragma unroll
      for (int c = 0; c < 4; ++c){
        union { uint4v v; u64 d[2]; } uq; uq.v = qh[c];
        *(u64*)(ldsH + (wv*4+c)*132 + lane*2) =
            (u64)strip2(uq.d[0]) | ((u64)strip2(uq.d[1]) << 32);
      }
    }
    __syncthreads();

    // ack prev-layer consumption every 8 steps (values were tag-checked ->
    // loads complete; relaxed agent flag is sufficient for the WAR watermark)
    if (HASX && wrap && ((t & 7) == 7) && lane == 0) st_flag(ackPrevW, t+1);

    if constexpr (HASX){
      #pragma unroll
      for (int k = 0; k < NKX; ++k) Bx[k] = lds_frag(ldsX, l15, quad*8 + k*32);
    }
    short8 Bh[8];
    if (t == 0){
      const float* ph = h0 + ((size_t)l*NB + bloc)*NH + quad*8;
      #pragma unroll
      for (int k = 0; k < 8; ++k) Bh[k] = ld8f_frag(ph + k*32);
    } else {
      #pragma unroll
      for (int k = 0; k < 8; ++k) Bh[k] = lds_frag(ldsH, l15, quad*8 + k*32);
    }

    // ---- MFMAs: x-part then h-part ----
    f32x4 a0 = {0,0,0,0}, a1 = {0,0,0,0}, a2 = {0,0,0,0}, a3 = {0,0,0,0};
    #pragma unroll
    for (int k = 0; k < NKX; ++k){
      a0 = __builtin_amdgcn_mfma_f32_16x16x32_bf16(A[0][k], Bx[k], a0, 0, 0, 0);
      a1 = __builtin_amdgcn_mfma_f32_16x16x32_bf16(A[1][k], Bx[k], a1, 0, 0, 0);
      a2 = __builtin_amdgcn_mfma_f32_16x16x32_bf16(A[2][k], Bx[k], a2, 0, 0, 0);
      a3 = __builtin_amdgcn_mfma_f32_16x16x32_bf16(A[3][k], Bx[k], a3, 0, 0, 0);
    }
    #pragma unroll
    for (int k = 0; k < 8; ++k){
      a0 = __builtin_amdgcn_mfma_f32_16x16x32_bf16(A[0][NKX+k], Bh[k], a0, 0, 0, 0);
      a1 = __builtin_amdgcn_mfma_f32_16x16x32_bf16(A[1][NKX+k], Bh[k], a1, 0, 0, 0);
      a2 = __builtin_amdgcn_mfma_f32_16x16x32_bf16(A[2][NKX+k], Bh[k], a2, 0, 0, 0);
      a3 = __builtin_amdgcn_mfma_f32_16x16x32_bf16(A[3][NKX+k], Bh[k], a3, 0, 0, 0);
    }

    // ---- fused gate nonlinearities + state update ----
    float hv[4];
    #pragma unroll
    for (int r = 0; r < 4; ++r){
      float ig = sigmf(a0[r] + bsv[0][r]);
      float fg = sigmf(a1[r] + bsv[1][r]);
      float gv = tanhfast(a2[r] + bsv[2][r]);
      float og = sigmf(a3[r] + bsv[3][r]);
      float cn = fg*cc[r] + ig*gv;
      cc[r] = cn;
      hv[r] = og * tanhfast(cn);
    }

    // ---- publish: one 16B self-tagged dual-scope store (L2 leg first) ----
    {
      const unsigned otag = (unsigned)(t+1);
      uint4v pv;
      pv[0] = tagw(hv[0], otag); pv[1] = tagw(hv[1], otag);
      pv[2] = tagw(hv[2], otag); pv[3] = tagw(hv[3], otag);
      st16_pub(ringOwn + (size_t)slot*TSLOT_U64 + (size_t)bloc*128 + s*8 + quad*2, pv);
    }
    if (t == NT-1){
      f32x4 ov; ov[0]=hv[0]; ov[1]=hv[1]; ov[2]=hv[2]; ov[3]=hv[3];
      *(f32x4*)(out + ((size_t)l*NB + bloc)*NH + jcol) = ov;
    }
  }
}

__global__ __launch_bounds__(256, 1)
void lstm_pipe(const float* __restrict__ x,   const float* __restrict__ h0,
               const float* __restrict__ c0,  const float* __restrict__ wih0,
               const float* __restrict__ wih, const float* __restrict__ whh,
               const float* __restrict__ bih, const float* __restrict__ bhh,
               float* __restrict__ out, int* __restrict__ acks,
               u64* __restrict__ ring, int Wv)
{
  // XCD clustering: bid = bg + 8*(l*4 + b) -> with bid%8 XCD round-robin the
  // whole pipeline of batch-group bg (24 blocks) shares one XCD/L2. Speed
  // heuristic only: the sc0 sc1 authoritative samples keep any mapping correct.
  __shared__ unsigned ldsb[4][2112];   // [buf2][x/h][16 rows x 132 u32]
  const int bid  = blockIdx.x;
  const int bg   = bid & 7;
  const int j    = bid >> 3;
  const int l    = j >> 2;
  const int b    = j & 3;
  const int lane = threadIdx.x & 63;
  const int wv   = threadIdx.x >> 6;
  const int s    = b*4 + wv;          // this wave's slice (0..15)

  if (l == 0)
    lstm_run<4>(x, h0, c0, wih0, whh, bih, bhh,
                out, acks, ring, ldsb, Wv, 0, bg, s, wv, lane);
  else
    lstm_run<8>(x, h0, c0,
                wih + (size_t)(l-1)*(4*NH*NH),
                whh + (size_t)l*(4*NH*NH),
                bih + (size_t)l*(4*NH),
                bhh + (size_t)l*(4*NH),
                out, acks, ring, ldsb, Wv, l, bg, s, wv, lane);
}

extern "C" void kernel_launch(void* const* d_in, const int* in_sizes, int n_in,
                              void* d_out, int out_size, void* d_ws, size_t ws_size,
                              hipStream_t stream)
{
  (void)in_sizes; (void)n_in; (void)out_size;
  const float* x    = (const float*)d_in[0];
  const float* h0   = (const float*)d_in[1];
  const float* c0   = (const float*)d_in[2];
  const float* wih0 = (const float*)d_in[3];
  const float* wih  = (const float*)d_in[4];
  const float* whh  = (const float*)d_in[5];
  const float* bih  = (const float*)d_in[6];
  const float* bhh  = (const float*)d_in[7];

  // Ring depth 32 (25 MB tagged). Own-h cohort is lockstep (skew <= 1);
  // cross-layer wrap uses amortized acks.
  int Wv = 32;
  size_t ringB;
  for (;;){
    ringB = (size_t)NLAYER*Wv*TSLOT_U64*8;
    if (8192 + ringB <= ws_size || Wv <= 8) break;
    Wv >>= 1;
  }

  int* acks = (int*)d_ws;                    // 768 ints, padded to 8KB
  u64* ring = (u64*)((char*)d_ws + 8192);

  // Ring MUST be cleared every launch: graph replay would otherwise find the
  // previous run's tags (identical t+1 pattern) and accept stale data.
  // Tag 0 never validates (expected tags are >= 1).
  (void)hipMemsetAsync(d_ws, 0, 8192 + ringB, stream);
  hipLaunchKernelGGL(lstm_pipe, dim3(NBLK), dim3(256), 0, stream,
                     x, h0, c0, wih0, wih, whh, bih, bhh,
                     (float*)d_out, acks, ring, Wv);
}